// Round 9
// baseline (105.894 us; speedup 1.0000x reference)
//
#include <hip/hip_runtime.h>

#define N_NODES 100000
#define BATCH   64
#define MID     32
#define LSTRIDE 80                    // h1 row stride (bytes)
#define WLDS    (64 * LSTRIDE + 512)  // per-wave LDS: 64 h1 rows + z-buffer (64*8B)
#define TOTAL   (BATCH * N_NODES)
#define CHF     (N_NODES * 3)         // floats per channel per batch

typedef __attribute__((ext_vector_type(2))) __fp16 h2v;
typedef _Float16 __attribute__((ext_vector_type(8))) f16x8;
typedef float __attribute__((ext_vector_type(4))) f32x4;

union H2U  { h2v h; unsigned int u; };
union U4H8 { uint4 u; f16x8 h; };

// wf[0..63]   : W2^T A-frag, j-tile 0   (row j = lane&15, k-slot (lane>>4)*8+m = cin)
// wf[64..127] : W2^T A-frag, j-tile 1
// wf[128..191]: W3^T A-frag (row c = lane&15, k-slot (q4,m) -> j = m<4 ? 4q4+m : 16+4q4+m-4;
//               rows c>=3 zero) — matches the k-perm of the acc-register B-operand.
// aux[0..47]  : W1 packed f16 pairs  w1p[k*16+m] = pack(W1[k][2m], W1[k][2m+1])
// aux[48..63] : b1 packed f16 pairs
__global__ void prep_weights(const float* __restrict__ W1, const float* __restrict__ b1,
                             const float* __restrict__ W2, const float* __restrict__ W3,
                             uint4* __restrict__ wf, unsigned int* __restrict__ aux) {
    int t = threadIdx.x;
    if (t < 128) {
        int grp = t >> 6, l = t & 63;
        int j = (l & 15) + 16 * grp, k0 = (l >> 4) * 8;
        unsigned int pk[4];
#pragma unroll
        for (int m = 0; m < 4; ++m) {
            H2U a; a.h = __builtin_amdgcn_cvt_pkrtz(W2[(k0 + 2*m) * MID + j],
                                                    W2[(k0 + 2*m + 1) * MID + j]);
            pk[m] = a.u;
        }
        wf[t] = make_uint4(pk[0], pk[1], pk[2], pk[3]);
    } else if (t < 192) {
        int l = t & 63;
        int c = l & 15, q4 = l >> 4;
        unsigned int pk[4];
#pragma unroll
        for (int mp = 0; mp < 4; ++mp) {
            int jb = (mp < 2) ? (4*q4 + 2*mp) : (16 + 4*q4 + 2*(mp - 2));
            float x0 = (c < 3) ? W3[jb * 6 + c] : 0.f;
            float x1 = (c < 3) ? W3[(jb + 1) * 6 + c] : 0.f;
            H2U a; a.h = __builtin_amdgcn_cvt_pkrtz(x0, x1);
            pk[mp] = a.u;
        }
        wf[128 + l] = make_uint4(pk[0], pk[1], pk[2], pk[3]);
    } else if (t < 240) {
        int i = t - 192;               // w1p
        int k = i >> 4, m = i & 15;
        H2U a; a.h = __builtin_amdgcn_cvt_pkrtz(W1[k * MID + 2*m], W1[k * MID + 2*m + 1]);
        aux[i] = a.u;
    } else {
        int m = t - 240;               // b1p
        H2U a; a.h = __builtin_amdgcn_cvt_pkrtz(b1[2*m], b1[2*m + 1]);
        aux[48 + m] = a.u;
    }
}

// Softmax is degenerate (dst bijection -> alpha == 1 exactly); q/Wq/key unused.
// 4 positions/thread: all global I/O is dense 16B-aligned dwordx4 (N%4==0 makes
// every thread's 48B slice aligned). Wave processes its 256 positions in 4 chunks
// of 64 LDS rows (row = lane), reusing the same wave-private buffer (in-order DS
// pipe, no barriers). p-side: chunk 0 from neighbor-thread shuffle, chunks 1-3
// from the thread's OWN registers. MFMA core identical to the verified R8 kernel.
__global__ __launch_bounds__(256) void xattn_kernel(
    const float* __restrict__ in,
    const unsigned int* __restrict__ aux,   // w1p / b1p
    const float* __restrict__ b2,
    const uint4* __restrict__ wf,
    const float* __restrict__ Wp,
    float* __restrict__ out)
{
    __shared__ __attribute__((aligned(16))) char ldsbuf[4 * WLDS];   // 22528 B
    int tid  = threadIdx.x;
    int lane = tid & 63;
    int wave = tid >> 6;
    char* L  = ldsbuf + wave * WLDS;        // h1 rows [64][LSTRIDE]
    char* ZB = L + 64 * LSTRIDE;            // z-buffer [64][8B]

    int gt   = blockIdx.x * 256 + tid;      // grid*4 covers exactly B*N
    int idx4 = gt * 4;                      // first of this thread's 4 positions
    int b  = idx4 / N_NODES;
    int n0 = idx4 - b * N_NODES;            // multiple of 4; thread never straddles batches

    const float* inb  = in  + (size_t)b * (3u * CHF / 3u) * 3u;   // b * 3*CHF
    float*       outb = out + (size_t)b * 3u * CHF;

    // ---- dense aligned loads: node, ch1, edge (3x dwordx4 each) ----
    const f32x4* npv = (const f32x4*)(inb + (size_t)n0 * 3);
    f32x4 nda = npv[0], ndb = npv[1], ndc = npv[2];
    const f32x4* c1pv = (const f32x4*)(inb + CHF + (size_t)n0 * 3);
    f32x4 c1a = c1pv[0], c1b = c1pv[1], c1c = c1pv[2];
    const f32x4* edpv = (const f32x4*)(inb + 2 * CHF + (size_t)n0 * 3);
    f32x4 eda = edpv[0], edb = edpv[1], edc = edpv[2];

    // ---- dense pass-through stores (ch1, ch2) ----
    {
        f32x4* o1 = (f32x4*)(outb + CHF + (size_t)n0 * 3);
        o1[0] = c1a; o1[1] = c1b; o1[2] = c1c;
        f32x4* o2 = (f32x4*)(outb + 2 * CHF + (size_t)n0 * 3);
        o2[0] = eda; o2[1] = edb; o2[2] = edc;
    }

    // register arrays, all statically indexed after unroll
    float nd[12] = {nda[0],nda[1],nda[2],nda[3], ndb[0],ndb[1],ndb[2],ndb[3], ndc[0],ndc[1],ndc[2],ndc[3]};
    float eg[12] = {eda[0],eda[1],eda[2],eda[3], edb[0],edb[1],edb[2],edb[3], edc[0],edc[1],edc[2],edc[3]};

    // ---- chunk-0 p-data: neighbor thread's position 3 via f16-packed shuffle ----
    H2U s0_, s1_, s2_;
    s0_.h = __builtin_amdgcn_cvt_pkrtz(nd[9], nd[10]);
    s1_.h = __builtin_amdgcn_cvt_pkrtz(nd[11], eg[9]);
    s2_.h = __builtin_amdgcn_cvt_pkrtz(eg[10], eg[11]);
    unsigned int t0 = __shfl_up(s0_.u, 1);
    unsigned int t1 = __shfl_up(s1_.u, 1);
    unsigned int t2 = __shfl_up(s2_.u, 1);
    float p0n0, p0n1, p0n2, p0e0, p0e1, p0e2;
    if (lane == 0 || n0 == 0) {             // prev thread unreachable / batch start
        int p = (n0 == 0) ? (N_NODES - 1) : (n0 - 1);
        const float* np_ = inb + (size_t)p * 3;
        const float* epp = inb + 2 * CHF + (size_t)p * 3;
        p0n0 = np_[0]; p0n1 = np_[1]; p0n2 = np_[2];
        p0e0 = epp[0]; p0e1 = epp[1]; p0e2 = epp[2];
    } else {
        H2U u0, u1, u2; u0.u = t0; u1.u = t1; u2.u = t2;
        p0n0 = (float)u0.h[0]; p0n1 = (float)u0.h[1]; p0n2 = (float)u1.h[0];
        p0e0 = (float)u1.h[1]; p0e1 = (float)u2.h[0]; p0e2 = (float)u2.h[1];
    }

    // ---- invariants for the MFMA core (verbatim R8, row = lane) ----
    int r16 = lane & 15;   // C-col = row-in-tile / B-col
    int q4  = lane >> 4;   // k-group / C-row-group
    U4H8 wb20; wb20.u = wf[lane];
    U4H8 wb21; wb21.u = wf[64 + lane];
    U4H8 wb3;  wb3.u  = wf[128 + lane];
    f32x4 bi0 = *(const f32x4*)(b2 + 4*q4);
    f32x4 bi1 = *(const f32x4*)(b2 + 16 + 4*q4);
    h2v zz = {(__fp16)0.0f, (__fp16)0.0f};

    float vo[12];

#pragma unroll
    for (int r = 0; r < 4; ++r) {
        // p-side for this chunk's position (n0 + r)
        float pe0 = (r == 0) ? p0e0 : eg[3*(r-1) + 0];
        float pe1 = (r == 0) ? p0e1 : eg[3*(r-1) + 1];
        float pe2 = (r == 0) ? p0e2 : eg[3*(r-1) + 2];
        float pn0 = (r == 0) ? p0n0 : nd[3*(r-1) + 0];
        float pn1 = (r == 0) ? p0n1 : nd[3*(r-1) + 1];
        float pn2 = (r == 0) ? p0n2 : nd[3*(r-1) + 2];

        // ---- layer 1: packed f16, relu -> LDS row [lane][32 f16] ----
        h2v eh0 = __builtin_amdgcn_cvt_pkrtz(pe0, pe0);
        h2v eh1 = __builtin_amdgcn_cvt_pkrtz(pe1, pe1);
        h2v eh2 = __builtin_amdgcn_cvt_pkrtz(pe2, pe2);
        unsigned int hp[16];
#pragma unroll
        for (int m = 0; m < 16; ++m) {
            H2U acc, w0, w1_, w2_;
            acc.u = aux[48 + m];
            w0.u  = aux[m];
            w1_.u = aux[16 + m];
            w2_.u = aux[32 + m];
            acc.h = eh0 * w0.h + acc.h;
            acc.h = eh1 * w1_.h + acc.h;
            acc.h = eh2 * w2_.h + acc.h;
            acc.h = __builtin_elementwise_max(acc.h, zz);
            hp[m] = acc.u;
        }
        {
            uint4* row = (uint4*)(L + lane * LSTRIDE);
            row[0] = make_uint4(hp[0],  hp[1],  hp[2],  hp[3]);
            row[1] = make_uint4(hp[4],  hp[5],  hp[6],  hp[7]);
            row[2] = make_uint4(hp[8],  hp[9],  hp[10], hp[11]);
            row[3] = make_uint4(hp[12], hp[13], hp[14], hp[15]);
        }

        // ---- swapped MFMA2 -> reg-pack -> swapped MFMA3 -> z-write (R8 core) ----
#pragma unroll
        for (int pt = 0; pt < 4; ++pt) {
            U4H8 hB; hB.u = *(const uint4*)(L + (pt*16 + r16) * LSTRIDE + q4 * 16);
            f32x4 acc0 = bi0;
            f32x4 acc1 = bi1;
            acc0 = __builtin_amdgcn_mfma_f32_16x16x32_f16(wb20.h, hB.h, acc0, 0, 0, 0);
            acc1 = __builtin_amdgcn_mfma_f32_16x16x32_f16(wb21.h, hB.h, acc1, 0, 0, 0);

            H2U g0, g1, g2, g3;
            g0.h = __builtin_elementwise_max(__builtin_amdgcn_cvt_pkrtz(acc0[0], acc0[1]), zz);
            g1.h = __builtin_elementwise_max(__builtin_amdgcn_cvt_pkrtz(acc0[2], acc0[3]), zz);
            g2.h = __builtin_elementwise_max(__builtin_amdgcn_cvt_pkrtz(acc1[0], acc1[1]), zz);
            g3.h = __builtin_elementwise_max(__builtin_amdgcn_cvt_pkrtz(acc1[2], acc1[3]), zz);
            U4H8 b3f; b3f.u = make_uint4(g0.u, g1.u, g2.u, g3.u);

            f32x4 c3 = __builtin_amdgcn_mfma_f32_16x16x32_f16(wb3.h, b3f.h,
                                                              (f32x4){0.f,0.f,0.f,0.f}, 0, 0, 0);
            if (q4 == 0) {
                H2U za; za.h = __builtin_amdgcn_cvt_pkrtz(c3[0], c3[1]);
                H2U zb; zb.h = __builtin_amdgcn_cvt_pkrtz(c3[2], 0.f);
                *(uint2*)(ZB + (pt*16 + r16) * 8) = make_uint2(za.u, zb.u);
            }
        }

        // ---- z = r . node[p];  vo[3r..3r+2] = Wp . [z, node[n0+r]] ----
        uint2 zr = *(const uint2*)(ZB + lane * 8);
        H2U za, zb; za.u = zr.x; zb.u = zr.y;
        float z = fmaf((float)za.h[0], pn0,
                  fmaf((float)za.h[1], pn1, (float)zb.h[0] * pn2));

        float qn0 = nd[3*r + 0], qn1 = nd[3*r + 1], qn2 = nd[3*r + 2];
#pragma unroll
        for (int o = 0; o < 3; ++o) {
            float v = Wp[o*4 + 0] * z;
            v = fmaf(Wp[o*4 + 1], qn0, v);
            v = fmaf(Wp[o*4 + 2], qn1, v);
            v = fmaf(Wp[o*4 + 3], qn2, v);
            vo[3*r + o] = v;
        }
    }

    // ---- dense aligned out0 store (3x dwordx4 = 4 positions) ----
    f32x4* o0 = (f32x4*)(outb + (size_t)n0 * 3);
    o0[0] = (f32x4){vo[0], vo[1], vo[2],  vo[3]};
    o0[1] = (f32x4){vo[4], vo[5], vo[6],  vo[7]};
    o0[2] = (f32x4){vo[8], vo[9], vo[10], vo[11]};
}

extern "C" void kernel_launch(void* const* d_in, const int* in_sizes, int n_in,
                              void* d_out, int out_size, void* d_ws, size_t ws_size,
                              hipStream_t stream) {
    const float* in = (const float*)d_in[0];
    const float* W1 = (const float*)d_in[1];
    const float* b1 = (const float*)d_in[2];
    const float* W2 = (const float*)d_in[3];
    const float* b2 = (const float*)d_in[4];
    const float* W3 = (const float*)d_in[5];
    // d_in[6] = Wq — provably unused (softmax weights are exactly 1)
    const float* Wp = (const float*)d_in[7];
    float* out = (float*)d_out;

    uint4* wf = (uint4*)d_ws;                        // 192 * 16 B
    unsigned int* aux = (unsigned int*)(wf + 192);   // 64 * 4 B
    hipLaunchKernelGGL(prep_weights, dim3(1), dim3(256), 0, stream, W1, b1, W2, W3, wf, aux);

    int blocks = TOTAL / 1024;   // 6250, exact (256 threads * 4 positions)
    hipLaunchKernelGGL(xattn_kernel, dim3(blocks), dim3(256), 0, stream,
                       in, aux, b2, wf, Wp, out);
}

// Round 10
// 100.250 us; speedup vs baseline: 1.0563x; 1.0563x over previous
//
#include <hip/hip_runtime.h>

#define N_NODES 100000
#define BATCH   64
#define MID     32
#define LSTRIDE 80                    // h1 row stride (bytes)
#define WLDS    (64 * LSTRIDE + 512)  // per-wave LDS: h1 rows + z-buffer (64*8B)
#define TOTAL   (BATCH * N_NODES)
#define CHF     (N_NODES * 3)         // floats per channel per batch
#define CH_U4   (CHF / 4)             // 75000 uint4 per channel per batch
#define CPB     37                    // copy blocks per batch (37*2048 >= 75000)
#define NCOPY   (CPB * BATCH)         // 2368 copy blocks
#define NCOMP   (TOTAL / 256)         // 25000 compute blocks
#define NGRID   (NCOPY + NCOMP)       // 27368

typedef __attribute__((ext_vector_type(2))) __fp16 h2v;
typedef _Float16 __attribute__((ext_vector_type(8))) f16x8;
typedef float __attribute__((ext_vector_type(4))) f32x4;
typedef float __attribute__((ext_vector_type(2))) f32x2;

union H2U  { h2v h; unsigned int u; };
union U4H8 { uint4 u; f16x8 h; };

// align-4 vector wrappers: (...,3) f32 layout is only 4B-aligned
struct __attribute__((packed, aligned(4))) F4u { f32x4 v; };
struct __attribute__((packed, aligned(4))) F2u { f32x2 v; };

// wf[0..63]   : W2^T A-frag, j-tile 0   (row j = lane&15, k-slot (lane>>4)*8+m = cin)
// wf[64..127] : W2^T A-frag, j-tile 1
// wf[128..191]: W3^T A-frag (row c = lane&15, k-slot (q4,m) -> j = m<4 ? 4q4+m : 16+4q4+m-4;
//               rows c>=3 zero) — matches the k-perm of the acc-register B-operand.
// aux[0..47]  : W1 packed f16 pairs; aux[48..63]: b1 packed f16 pairs
__global__ void prep_weights(const float* __restrict__ W1, const float* __restrict__ b1,
                             const float* __restrict__ W2, const float* __restrict__ W3,
                             uint4* __restrict__ wf, unsigned int* __restrict__ aux) {
    int t = threadIdx.x;
    if (t < 128) {
        int grp = t >> 6, l = t & 63;
        int j = (l & 15) + 16 * grp, k0 = (l >> 4) * 8;
        unsigned int pk[4];
#pragma unroll
        for (int m = 0; m < 4; ++m) {
            H2U a; a.h = __builtin_amdgcn_cvt_pkrtz(W2[(k0 + 2*m) * MID + j],
                                                    W2[(k0 + 2*m + 1) * MID + j]);
            pk[m] = a.u;
        }
        wf[t] = make_uint4(pk[0], pk[1], pk[2], pk[3]);
    } else if (t < 192) {
        int l = t & 63;
        int c = l & 15, q4 = l >> 4;
        unsigned int pk[4];
#pragma unroll
        for (int mp = 0; mp < 4; ++mp) {
            int jb = (mp < 2) ? (4*q4 + 2*mp) : (16 + 4*q4 + 2*(mp - 2));
            float x0 = (c < 3) ? W3[jb * 6 + c] : 0.f;
            float x1 = (c < 3) ? W3[(jb + 1) * 6 + c] : 0.f;
            H2U a; a.h = __builtin_amdgcn_cvt_pkrtz(x0, x1);
            pk[mp] = a.u;
        }
        wf[128 + l] = make_uint4(pk[0], pk[1], pk[2], pk[3]);
    } else if (t < 240) {
        int i = t - 192;
        int k = i >> 4, m = i & 15;
        H2U a; a.h = __builtin_amdgcn_cvt_pkrtz(W1[k * MID + 2*m], W1[k * MID + 2*m + 1]);
        aux[i] = a.u;
    } else {
        int m = t - 240;
        H2U a; a.h = __builtin_amdgcn_cvt_pkrtz(b1[2*m], b1[2*m + 1]);
        aux[48 + m] = a.u;
    }
}

// Heterogeneous grid: every 11th block (idx%11==5) is a PURE ch1-copy block
// (dense uint4 streaming, no LDS/MFMA, bottomless MLP to keep HBM queues full);
// the rest are R8-verified compute blocks (node/edge -> out0, ch2 copy).
// Softmax is degenerate (dst bijection -> alpha == 1 exactly); q/Wq/key unused.
__global__ __launch_bounds__(256) void xattn_kernel(
    const float* __restrict__ in,
    const unsigned int* __restrict__ aux,   // w1p / b1p
    const float* __restrict__ b2,
    const uint4* __restrict__ wf,
    const float* __restrict__ Wp,
    float* __restrict__ out)
{
    __shared__ __attribute__((aligned(16))) char ldsbuf[4 * WLDS];   // 22528 B
    int tid  = threadIdx.x;
    int bidx = blockIdx.x;

    // ---- copy blocks: ch1 of one batch, dense uint4, 8 per thread ----
    if (bidx % 11 == 5 && (bidx / 11) < NCOPY) {
        int cb    = bidx / 11;            // 0..NCOPY-1
        int batch = cb / CPB;
        int blk   = cb - batch * CPB;
        const uint4* src = (const uint4*)(in  + (size_t)batch * 3 * CHF + CHF);
        uint4*       dst = (uint4*)(out + (size_t)batch * 3 * CHF + CHF);
        int base = blk * 2048 + tid;
#pragma unroll
        for (int k = 0; k < 8; ++k) {
            int i = base + k * 256;
            if (i < CH_U4) dst[i] = src[i];
        }
        return;
    }

    // ---- compute blocks (verbatim R8 minus ch1) ----
    int cid  = bidx - min(NCOPY, (bidx + 5) / 11);   // 0..NCOMP-1 (bijective)
    int lane = tid & 63;
    int wave = tid >> 6;
    char* L  = ldsbuf + wave * WLDS;        // h1 rows [64][LSTRIDE]
    char* ZB = L + 64 * LSTRIDE;            // z-buffer [64][8B]

    int idx = cid * 256 + tid;              // position index, covers exactly B*N
    int b = idx / N_NODES;
    int n = idx - b * N_NODES;
    bool last  = (idx == TOTAL - 1);        // 4B-OOB exposure on the edge LOAD
    bool btail = (n == N_NODES - 1);        // ch2 overlap STORE would hit next batch's out0

    const float* inb  = in  + (size_t)b * 3 * CHF;
    float*       outb = out + (size_t)b * 3 * CHF;

    // ---- overlap-vec4 loads: node[n], edge[n] ----
    f32x4 ndv = ((const F4u*)(inb + (size_t)n * 3))->v;
    f32x4 edv;
    const float* e_ptr = inb + (size_t)2 * CHF + (size_t)n * 3;
    if (!last) edv = ((const F4u*)e_ptr)->v;
    else       edv = (f32x4){e_ptr[0], e_ptr[1], e_ptr[2], 0.f};

    float qn0 = ndv.x, qn1 = ndv.y, qn2 = ndv.z;

    // ---- ch2 pass-through store ----
    {
        float* o2p = outb + (size_t)2 * CHF + (size_t)n * 3;
        if (!btail) ((F4u*)o2p)->v = edv;  // 4th dword benign within batch
        else { o2p[0] = edv.x; o2p[1] = edv.y; o2p[2] = edv.z; }   // NEVER cross into out0
    }

    // ---- p-side via f16-packed shuffle (3 bpermutes); boundary lanes load ----
    H2U s0_, s1_, s2_;
    s0_.h = __builtin_amdgcn_cvt_pkrtz(qn0, qn1);     // (n0, n1)
    s1_.h = __builtin_amdgcn_cvt_pkrtz(qn2, edv.x);   // (n2, e0)
    s2_.h = __builtin_amdgcn_cvt_pkrtz(edv.y, edv.z); // (e1, e2)
    unsigned int t0 = __shfl_up(s0_.u, 1);
    unsigned int t1 = __shfl_up(s1_.u, 1);
    unsigned int t2 = __shfl_up(s2_.u, 1);
    if (lane == 0 || n == 0) {
        int p = (n == 0) ? (N_NODES - 1) : (n - 1);
        const float* np_ = inb + (size_t)p * 3;
        const float* epp = inb + (size_t)2 * CHF + (size_t)p * 3;
        H2U a, bb, c;
        a.h  = __builtin_amdgcn_cvt_pkrtz(np_[0], np_[1]);
        bb.h = __builtin_amdgcn_cvt_pkrtz(np_[2], epp[0]);
        c.h  = __builtin_amdgcn_cvt_pkrtz(epp[1], epp[2]);
        t0 = a.u; t1 = bb.u; t2 = c.u;
    }
    H2U u0, u1, u2; u0.u = t0; u1.u = t1; u2.u = t2;
    float pp0 = (float)u0.h[0], pp1 = (float)u0.h[1], pp2 = (float)u1.h[0];
    h2v eh0 = {u1.h[1], u1.h[1]};
    h2v eh1 = {u2.h[0], u2.h[0]};
    h2v eh2 = {u2.h[1], u2.h[1]};

    // ---- layer 1: packed f16 (v_pk_fma_f16), relu -> LDS rows [pos][32 f16] ----
    h2v zz = {(__fp16)0.0f, (__fp16)0.0f};
    unsigned int hp[16];
#pragma unroll
    for (int m = 0; m < 16; ++m) {
        H2U acc, w0, w1_, w2_;
        acc.u = aux[48 + m];
        w0.u  = aux[m];
        w1_.u = aux[16 + m];
        w2_.u = aux[32 + m];
        acc.h = eh0 * w0.h + acc.h;
        acc.h = eh1 * w1_.h + acc.h;
        acc.h = eh2 * w2_.h + acc.h;
        acc.h = __builtin_elementwise_max(acc.h, zz);
        hp[m] = acc.u;
    }
    {
        uint4* row = (uint4*)(L + lane * LSTRIDE);
        row[0] = make_uint4(hp[0],  hp[1],  hp[2],  hp[3]);
        row[1] = make_uint4(hp[4],  hp[5],  hp[6],  hp[7]);
        row[2] = make_uint4(hp[8],  hp[9],  hp[10], hp[11]);
        row[3] = make_uint4(hp[12], hp[13], hp[14], hp[15]);
    }

    // ---- per pos-tile: swapped MFMA2 -> reg-pack -> swapped MFMA3 -> z-write ----
    int r16 = lane & 15;   // C-col = position within tile / B-col
    int q4  = lane >> 4;   // k-group / C-row-group
    U4H8 wb20; wb20.u = wf[lane];
    U4H8 wb21; wb21.u = wf[64 + lane];
    U4H8 wb3;  wb3.u  = wf[128 + lane];
    f32x4 bi0 = *(const f32x4*)(b2 + 4*q4);        // b2[j], j = 4q4 + r  (C-rows)
    f32x4 bi1 = *(const f32x4*)(b2 + 16 + 4*q4);

#pragma unroll
    for (int pt = 0; pt < 4; ++pt) {
        U4H8 hB; hB.u = *(const uint4*)(L + (pt*16 + r16) * LSTRIDE + q4 * 16);
        f32x4 acc0 = bi0;
        f32x4 acc1 = bi1;
        acc0 = __builtin_amdgcn_mfma_f32_16x16x32_f16(wb20.h, hB.h, acc0, 0, 0, 0);
        acc1 = __builtin_amdgcn_mfma_f32_16x16x32_f16(wb21.h, hB.h, acc1, 0, 0, 0);

        // relu+pack in register: lane holds h2[pos][{4q4..4q4+3, 16+4q4..+3}] = B3' frag
        H2U g0, g1, g2, g3;
        g0.h = __builtin_elementwise_max(__builtin_amdgcn_cvt_pkrtz(acc0[0], acc0[1]), zz);
        g1.h = __builtin_elementwise_max(__builtin_amdgcn_cvt_pkrtz(acc0[2], acc0[3]), zz);
        g2.h = __builtin_elementwise_max(__builtin_amdgcn_cvt_pkrtz(acc1[0], acc1[1]), zz);
        g3.h = __builtin_elementwise_max(__builtin_amdgcn_cvt_pkrtz(acc1[2], acc1[3]), zz);
        U4H8 b3f; b3f.u = make_uint4(g0.u, g1.u, g2.u, g3.u);

        f32x4 c3 = __builtin_amdgcn_mfma_f32_16x16x32_f16(wb3.h, b3f.h,
                                                          (f32x4){0.f,0.f,0.f,0.f}, 0, 0, 0);

        // rows c = 4*q4 + r -> q4==0 lanes hold c=0..2 for position pt*16 + r16
        if (q4 == 0) {
            H2U za; za.h = __builtin_amdgcn_cvt_pkrtz(c3[0], c3[1]);
            H2U zb; zb.h = __builtin_amdgcn_cvt_pkrtz(c3[2], 0.f);
            *(uint2*)(ZB + (pt*16 + r16) * 8) = make_uint2(za.u, zb.u);
        }
    }

    // ---- tail: z = r . node[p]; out0 = Wp . [z, node[n]] ----
    uint2 zr = *(const uint2*)(ZB + lane * 8);
    H2U za, zb; za.u = zr.x; zb.u = zr.y;
    float z = fmaf((float)za.h[0], pp0,
              fmaf((float)za.h[1], pp1, (float)zb.h[0] * pp2));

    float vo[3];
#pragma unroll
    for (int o = 0; o < 3; ++o) {
        float v = Wp[o*4 + 0] * z;
        v = fmaf(Wp[o*4 + 1], qn0, v);
        v = fmaf(Wp[o*4 + 2], qn1, v);
        v = fmaf(Wp[o*4 + 3], qn2, v);
        vo[o] = v;
    }
    float* o0 = outb + (size_t)n * 3;
    ((F2u*)o0)->v = (f32x2){vo[0], vo[1]};   // dwordx2 (align 4) + dword
    o0[2] = vo[2];
}

extern "C" void kernel_launch(void* const* d_in, const int* in_sizes, int n_in,
                              void* d_out, int out_size, void* d_ws, size_t ws_size,
                              hipStream_t stream) {
    const float* in = (const float*)d_in[0];
    const float* W1 = (const float*)d_in[1];
    const float* b1 = (const float*)d_in[2];
    const float* W2 = (const float*)d_in[3];
    const float* b2 = (const float*)d_in[4];
    const float* W3 = (const float*)d_in[5];
    // d_in[6] = Wq — provably unused (softmax weights are exactly 1)
    const float* Wp = (const float*)d_in[7];
    float* out = (float*)d_out;

    uint4* wf = (uint4*)d_ws;                        // 192 * 16 B
    unsigned int* aux = (unsigned int*)(wf + 192);   // 64 * 4 B
    hipLaunchKernelGGL(prep_weights, dim3(1), dim3(256), 0, stream, W1, b1, W2, W3, wf, aux);

    hipLaunchKernelGGL(xattn_kernel, dim3(NGRID), dim3(256), 0, stream,
                       in, aux, b2, wf, Wp, out);
}

// Round 11
// 95.355 us; speedup vs baseline: 1.1105x; 1.0513x over previous
//
#include <hip/hip_runtime.h>

#define N_NODES 100000
#define BATCH   64
#define MID     32
#define LSTRIDE 80               // h1 row stride (bytes); bytes [64,80) of each row = ZB overlay
#define WLDS    (64 * LSTRIDE)   // per-wave LDS: 5120 B -> 4 waves = 20480 B = 8 blocks/CU
#define TOTAL   (BATCH * N_NODES)
#define CHF     (N_NODES * 3)    // floats per channel per batch

typedef __attribute__((ext_vector_type(2))) __fp16 h2v;
typedef _Float16 __attribute__((ext_vector_type(8))) f16x8;
typedef float __attribute__((ext_vector_type(4))) f32x4;
typedef float __attribute__((ext_vector_type(2))) f32x2;

union H2U  { h2v h; unsigned int u; };
union U4H8 { uint4 u; f16x8 h; };

// align-4 vector wrappers: (...,3) f32 layout is only 4B-aligned
struct __attribute__((packed, aligned(4))) F4u { f32x4 v; };
struct __attribute__((packed, aligned(4))) F2u { f32x2 v; };

// wf[0..63]   : W2^T A-frag, j-tile 0   (row j = lane&15, k-slot (lane>>4)*8+m = cin)
// wf[64..127] : W2^T A-frag, j-tile 1
// wf[128..191]: W3^T A-frag (row c = lane&15, k-slot (q4,m) -> j = m<4 ? 4q4+m : 16+4q4+m-4;
//               rows c>=3 zero) — matches the k-perm of the acc-register B-operand.
// aux[0..47]  : W1 packed f16 pairs; aux[48..63]: b1 packed f16 pairs
__global__ void prep_weights(const float* __restrict__ W1, const float* __restrict__ b1,
                             const float* __restrict__ W2, const float* __restrict__ W3,
                             uint4* __restrict__ wf, unsigned int* __restrict__ aux) {
    int t = threadIdx.x;
    if (t < 128) {
        int grp = t >> 6, l = t & 63;
        int j = (l & 15) + 16 * grp, k0 = (l >> 4) * 8;
        unsigned int pk[4];
#pragma unroll
        for (int m = 0; m < 4; ++m) {
            H2U a; a.h = __builtin_amdgcn_cvt_pkrtz(W2[(k0 + 2*m) * MID + j],
                                                    W2[(k0 + 2*m + 1) * MID + j]);
            pk[m] = a.u;
        }
        wf[t] = make_uint4(pk[0], pk[1], pk[2], pk[3]);
    } else if (t < 192) {
        int l = t & 63;
        int c = l & 15, q4 = l >> 4;
        unsigned int pk[4];
#pragma unroll
        for (int mp = 0; mp < 4; ++mp) {
            int jb = (mp < 2) ? (4*q4 + 2*mp) : (16 + 4*q4 + 2*(mp - 2));
            float x0 = (c < 3) ? W3[jb * 6 + c] : 0.f;
            float x1 = (c < 3) ? W3[(jb + 1) * 6 + c] : 0.f;
            H2U a; a.h = __builtin_amdgcn_cvt_pkrtz(x0, x1);
            pk[mp] = a.u;
        }
        wf[128 + l] = make_uint4(pk[0], pk[1], pk[2], pk[3]);
    } else if (t < 240) {
        int i = t - 192;
        int k = i >> 4, m = i & 15;
        H2U a; a.h = __builtin_amdgcn_cvt_pkrtz(W1[k * MID + 2*m], W1[k * MID + 2*m + 1]);
        aux[i] = a.u;
    } else {
        int m = t - 240;
        H2U a; a.h = __builtin_amdgcn_cvt_pkrtz(b1[2*m], b1[2*m + 1]);
        aux[48 + m] = a.u;
    }
}

// Softmax is degenerate (dst bijection -> alpha == 1 exactly); q/Wq/key unused.
// R8 structure verbatim EXCEPT: the z-buffer is folded into the h1 rows' LSTRIDE
// pad (bytes [64,80) of each row), shrinking LDS 22528 -> 20480 B per block ->
// exactly 8 blocks/CU (32 waves, was 7/28). Wave-private LDS; in-order per-wave
// DS pipe -> no barriers (reads touch [0,64), ZB lives in [64,80): disjoint).
__global__ __launch_bounds__(256) void xattn_kernel(
    const float* __restrict__ in,
    const unsigned int* __restrict__ aux,   // w1p / b1p
    const float* __restrict__ b2,
    const uint4* __restrict__ wf,
    const float* __restrict__ Wp,
    float* __restrict__ out)
{
    __shared__ __attribute__((aligned(16))) char ldsbuf[4 * WLDS];   // 20480 B
    int tid  = threadIdx.x;
    int lane = tid & 63;
    int wave = tid >> 6;
    char* L  = ldsbuf + wave * WLDS;        // h1 rows [64][LSTRIDE]; pad bytes 64..79 = ZB

    int idx = blockIdx.x * 256 + tid;       // grid covers exactly B*N
    int b = idx / N_NODES;
    int n = idx - b * N_NODES;
    bool last  = (idx == TOTAL - 1);        // 4B-OOB exposure on the edge LOAD
    bool btail = (n == N_NODES - 1);        // ch2 overlap STORE would hit next batch's out0

    const float* inb  = in  + (size_t)b * 3 * CHF;
    float*       outb = out + (size_t)b * 3 * CHF;

    // ---- overlap-vec4 loads: node[n], ch1[n], edge[n] ----
    f32x4 ndv = ((const F4u*)(inb + (size_t)n * 3))->v;
    f32x4 c1v = ((const F4u*)(inb + (size_t)CHF + (size_t)n * 3))->v;
    f32x4 edv;
    const float* e_ptr = inb + (size_t)2 * CHF + (size_t)n * 3;
    if (!last) edv = ((const F4u*)e_ptr)->v;
    else       edv = (f32x4){e_ptr[0], e_ptr[1], e_ptr[2], 0.f};

    float qn0 = ndv.x, qn1 = ndv.y, qn2 = ndv.z;

    // ---- pass-through stores (ch1, ch2) ----
    {
        float* o1p = outb + (size_t)CHF + (size_t)n * 3;
        ((F4u*)o1p)->v = c1v;              // 4th dword: benign (same value as neighbor's)
        float* o2p = outb + (size_t)2 * CHF + (size_t)n * 3;
        if (!btail) ((F4u*)o2p)->v = edv;  // 4th dword benign within batch
        else { o2p[0] = edv.x; o2p[1] = edv.y; o2p[2] = edv.z; }   // NEVER cross into out0
    }

    // ---- p-side via f16-packed shuffle (3 bpermutes); boundary lanes load ----
    H2U s0_, s1_, s2_;
    s0_.h = __builtin_amdgcn_cvt_pkrtz(qn0, qn1);     // (n0, n1)
    s1_.h = __builtin_amdgcn_cvt_pkrtz(qn2, edv.x);   // (n2, e0)
    s2_.h = __builtin_amdgcn_cvt_pkrtz(edv.y, edv.z); // (e1, e2)
    unsigned int t0 = __shfl_up(s0_.u, 1);
    unsigned int t1 = __shfl_up(s1_.u, 1);
    unsigned int t2 = __shfl_up(s2_.u, 1);
    if (lane == 0 || n == 0) {
        int p = (n == 0) ? (N_NODES - 1) : (n - 1);
        const float* np_ = inb + (size_t)p * 3;
        const float* epp = inb + (size_t)2 * CHF + (size_t)p * 3;
        H2U a, bb, c;
        a.h  = __builtin_amdgcn_cvt_pkrtz(np_[0], np_[1]);
        bb.h = __builtin_amdgcn_cvt_pkrtz(np_[2], epp[0]);
        c.h  = __builtin_amdgcn_cvt_pkrtz(epp[1], epp[2]);
        t0 = a.u; t1 = bb.u; t2 = c.u;
    }
    H2U u0, u1, u2; u0.u = t0; u1.u = t1; u2.u = t2;
    float pp0 = (float)u0.h[0], pp1 = (float)u0.h[1], pp2 = (float)u1.h[0];
    h2v eh0 = {u1.h[1], u1.h[1]};
    h2v eh1 = {u2.h[0], u2.h[0]};
    h2v eh2 = {u2.h[1], u2.h[1]};

    // ---- layer 1: packed f16 (v_pk_fma_f16), relu -> LDS rows [pos][32 f16] ----
    h2v zz = {(__fp16)0.0f, (__fp16)0.0f};
    unsigned int hp[16];
#pragma unroll
    for (int m = 0; m < 16; ++m) {
        H2U acc, w0, w1_, w2_;
        acc.u = aux[48 + m];
        w0.u  = aux[m];
        w1_.u = aux[16 + m];
        w2_.u = aux[32 + m];
        acc.h = eh0 * w0.h + acc.h;
        acc.h = eh1 * w1_.h + acc.h;
        acc.h = eh2 * w2_.h + acc.h;
        acc.h = __builtin_elementwise_max(acc.h, zz);
        hp[m] = acc.u;
    }
    {
        uint4* row = (uint4*)(L + lane * LSTRIDE);
        row[0] = make_uint4(hp[0],  hp[1],  hp[2],  hp[3]);
        row[1] = make_uint4(hp[4],  hp[5],  hp[6],  hp[7]);
        row[2] = make_uint4(hp[8],  hp[9],  hp[10], hp[11]);
        row[3] = make_uint4(hp[12], hp[13], hp[14], hp[15]);
    }

    // ---- per pos-tile: swapped MFMA2 -> reg-pack -> swapped MFMA3 -> z-write ----
    int r16 = lane & 15;   // C-col = position within tile / B-col
    int q4  = lane >> 4;   // k-group / C-row-group
    U4H8 wb20; wb20.u = wf[lane];
    U4H8 wb21; wb21.u = wf[64 + lane];
    U4H8 wb3;  wb3.u  = wf[128 + lane];
    f32x4 bi0 = *(const f32x4*)(b2 + 4*q4);        // b2[j], j = 4q4 + r  (C-rows)
    f32x4 bi1 = *(const f32x4*)(b2 + 16 + 4*q4);

#pragma unroll
    for (int pt = 0; pt < 4; ++pt) {
        U4H8 hB; hB.u = *(const uint4*)(L + (pt*16 + r16) * LSTRIDE + q4 * 16);
        f32x4 acc0 = bi0;
        f32x4 acc1 = bi1;
        acc0 = __builtin_amdgcn_mfma_f32_16x16x32_f16(wb20.h, hB.h, acc0, 0, 0, 0);
        acc1 = __builtin_amdgcn_mfma_f32_16x16x32_f16(wb21.h, hB.h, acc1, 0, 0, 0);

        // relu+pack in register: lane holds h2[pos][{4q4..4q4+3, 16+4q4..+3}] = B3' frag
        H2U g0, g1, g2, g3;
        g0.h = __builtin_elementwise_max(__builtin_amdgcn_cvt_pkrtz(acc0[0], acc0[1]), zz);
        g1.h = __builtin_elementwise_max(__builtin_amdgcn_cvt_pkrtz(acc0[2], acc0[3]), zz);
        g2.h = __builtin_elementwise_max(__builtin_amdgcn_cvt_pkrtz(acc1[0], acc1[1]), zz);
        g3.h = __builtin_elementwise_max(__builtin_amdgcn_cvt_pkrtz(acc1[2], acc1[3]), zz);
        U4H8 b3f; b3f.u = make_uint4(g0.u, g1.u, g2.u, g3.u);

        f32x4 c3 = __builtin_amdgcn_mfma_f32_16x16x32_f16(wb3.h, b3f.h,
                                                          (f32x4){0.f,0.f,0.f,0.f}, 0, 0, 0);

        // rows c = 4*q4 + r -> q4==0 lanes hold c=0..2 for position pos = pt*16 + r16.
        // ZB overlay: z of position pos lives in row pos>>1's pad, byte 64 + (pos&1)*8.
        if (q4 == 0) {
            int pos = pt*16 + r16;
            H2U za; za.h = __builtin_amdgcn_cvt_pkrtz(c3[0], c3[1]);
            H2U zb; zb.h = __builtin_amdgcn_cvt_pkrtz(c3[2], 0.f);
            *(uint2*)(L + (pos >> 1) * LSTRIDE + 64 + (pos & 1) * 8) = make_uint2(za.u, zb.u);
        }
    }

    // ---- tail: z = r . node[p]; out0 = Wp . [z, node[n]] ----
    uint2 zr = *(const uint2*)(L + (lane >> 1) * LSTRIDE + 64 + (lane & 1) * 8);
    H2U za, zb; za.u = zr.x; zb.u = zr.y;
    float z = fmaf((float)za.h[0], pp0,
              fmaf((float)za.h[1], pp1, (float)zb.h[0] * pp2));

    float vo[3];
#pragma unroll
    for (int o = 0; o < 3; ++o) {
        float v = Wp[o*4 + 0] * z;
        v = fmaf(Wp[o*4 + 1], qn0, v);
        v = fmaf(Wp[o*4 + 2], qn1, v);
        v = fmaf(Wp[o*4 + 3], qn2, v);
        vo[o] = v;
    }
    float* o0 = outb + (size_t)n * 3;
    ((F2u*)o0)->v = (f32x2){vo[0], vo[1]};   // dwordx2 (align 4) + dword
    o0[2] = vo[2];
}

extern "C" void kernel_launch(void* const* d_in, const int* in_sizes, int n_in,
                              void* d_out, int out_size, void* d_ws, size_t ws_size,
                              hipStream_t stream) {
    const float* in = (const float*)d_in[0];
    const float* W1 = (const float*)d_in[1];
    const float* b1 = (const float*)d_in[2];
    const float* W2 = (const float*)d_in[3];
    const float* b2 = (const float*)d_in[4];
    const float* W3 = (const float*)d_in[5];
    // d_in[6] = Wq — provably unused (softmax weights are exactly 1)
    const float* Wp = (const float*)d_in[7];
    float* out = (float*)d_out;

    uint4* wf = (uint4*)d_ws;                        // 192 * 16 B
    unsigned int* aux = (unsigned int*)(wf + 192);   // 64 * 4 B
    hipLaunchKernelGGL(prep_weights, dim3(1), dim3(256), 0, stream, W1, b1, W2, W3, wf, aux);

    int blocks = TOTAL / 256;   // 25000, exact
    hipLaunchKernelGGL(xattn_kernel, dim3(blocks), dim3(256), 0, stream,
                       in, aux, b2, wf, Wp, out);
}

// Round 12
// 80.486 us; speedup vs baseline: 1.3157x; 1.1847x over previous
//
#include <hip/hip_runtime.h>

#define N_NODES 100000
#define BATCH   64
#define MID     32
#define LSTRIDE 80               // h1 row stride (bytes); bytes [64,80) of each row = ZB overlay
#define WLDS    (64 * LSTRIDE)   // per-wave LDS: 5120 B -> 4 waves = 20480 B = 8 blocks/CU
#define TOTAL   (BATCH * N_NODES)
#define CHF     (N_NODES * 3)    // floats per channel per batch

typedef __attribute__((ext_vector_type(2))) __fp16 h2v;
typedef _Float16 __attribute__((ext_vector_type(8))) f16x8;
typedef float __attribute__((ext_vector_type(4))) f32x4;
typedef float __attribute__((ext_vector_type(2))) f32x2;

union H2U  { h2v h; unsigned int u; };
union U4H8 { uint4 u; f16x8 h; };

// align-4 vector wrappers: (...,3) f32 layout is only 4B-aligned
struct __attribute__((packed, aligned(4))) F4u { f32x4 v; };

// under-aligned vector typedefs for nontemporal stores
typedef f32x4 f32x4a4 __attribute__((aligned(4)));
typedef f32x2 f32x2a4 __attribute__((aligned(4)));

__device__ __forceinline__ void nts4(float* p, f32x4 v) {
    __builtin_nontemporal_store(v, (f32x4a4*)p);
}
__device__ __forceinline__ void nts2(float* p, f32x2 v) {
    __builtin_nontemporal_store(v, (f32x2a4*)p);
}
__device__ __forceinline__ void nts1(float* p, float v) {
    __builtin_nontemporal_store(v, p);
}

// wf[0..63]   : W2^T A-frag, j-tile 0   (row j = lane&15, k-slot (lane>>4)*8+m = cin)
// wf[64..127] : W2^T A-frag, j-tile 1
// wf[128..191]: W3^T A-frag (row c = lane&15, k-slot (q4,m) -> j = m<4 ? 4q4+m : 16+4q4+m-4;
//               rows c>=3 zero) — matches the k-perm of the acc-register B-operand.
// aux[0..47]  : W1 packed f16 pairs; aux[48..63]: b1 packed f16 pairs
__global__ void prep_weights(const float* __restrict__ W1, const float* __restrict__ b1,
                             const float* __restrict__ W2, const float* __restrict__ W3,
                             uint4* __restrict__ wf, unsigned int* __restrict__ aux) {
    int t = threadIdx.x;
    if (t < 128) {
        int grp = t >> 6, l = t & 63;
        int j = (l & 15) + 16 * grp, k0 = (l >> 4) * 8;
        unsigned int pk[4];
#pragma unroll
        for (int m = 0; m < 4; ++m) {
            H2U a; a.h = __builtin_amdgcn_cvt_pkrtz(W2[(k0 + 2*m) * MID + j],
                                                    W2[(k0 + 2*m + 1) * MID + j]);
            pk[m] = a.u;
        }
        wf[t] = make_uint4(pk[0], pk[1], pk[2], pk[3]);
    } else if (t < 192) {
        int l = t & 63;
        int c = l & 15, q4 = l >> 4;
        unsigned int pk[4];
#pragma unroll
        for (int mp = 0; mp < 4; ++mp) {
            int jb = (mp < 2) ? (4*q4 + 2*mp) : (16 + 4*q4 + 2*(mp - 2));
            float x0 = (c < 3) ? W3[jb * 6 + c] : 0.f;
            float x1 = (c < 3) ? W3[(jb + 1) * 6 + c] : 0.f;
            H2U a; a.h = __builtin_amdgcn_cvt_pkrtz(x0, x1);
            pk[mp] = a.u;
        }
        wf[128 + l] = make_uint4(pk[0], pk[1], pk[2], pk[3]);
    } else if (t < 240) {
        int i = t - 192;
        int k = i >> 4, m = i & 15;
        H2U a; a.h = __builtin_amdgcn_cvt_pkrtz(W1[k * MID + 2*m], W1[k * MID + 2*m + 1]);
        aux[i] = a.u;
    } else {
        int m = t - 240;
        H2U a; a.h = __builtin_amdgcn_cvt_pkrtz(b1[2*m], b1[2*m + 1]);
        aux[48 + m] = a.u;
    }
}

// Softmax is degenerate (dst bijection -> alpha == 1 exactly); q/Wq/key unused.
// R11 structure verbatim EXCEPT: ALL output stores are NON-TEMPORAL, so the
// 225 MB write stream stops evicting the (L3-resident) input between replays.
// Wave-private LDS; in-order per-wave DS pipe -> no barriers.
__global__ __launch_bounds__(256) void xattn_kernel(
    const float* __restrict__ in,
    const unsigned int* __restrict__ aux,   // w1p / b1p
    const float* __restrict__ b2,
    const uint4* __restrict__ wf,
    const float* __restrict__ Wp,
    float* __restrict__ out)
{
    __shared__ __attribute__((aligned(16))) char ldsbuf[4 * WLDS];   // 20480 B
    int tid  = threadIdx.x;
    int lane = tid & 63;
    int wave = tid >> 6;
    char* L  = ldsbuf + wave * WLDS;        // h1 rows [64][LSTRIDE]; pad bytes 64..79 = ZB

    int idx = blockIdx.x * 256 + tid;       // grid covers exactly B*N
    int b = idx / N_NODES;
    int n = idx - b * N_NODES;
    bool last  = (idx == TOTAL - 1);        // 4B-OOB exposure on the edge LOAD
    bool btail = (n == N_NODES - 1);        // ch2 overlap STORE would hit next batch's out0

    const float* inb  = in  + (size_t)b * 3 * CHF;
    float*       outb = out + (size_t)b * 3 * CHF;

    // ---- overlap-vec4 loads: node[n], ch1[n], edge[n] ----
    f32x4 ndv = ((const F4u*)(inb + (size_t)n * 3))->v;
    f32x4 c1v = ((const F4u*)(inb + (size_t)CHF + (size_t)n * 3))->v;
    f32x4 edv;
    const float* e_ptr = inb + (size_t)2 * CHF + (size_t)n * 3;
    if (!last) edv = ((const F4u*)e_ptr)->v;
    else       edv = (f32x4){e_ptr[0], e_ptr[1], e_ptr[2], 0.f};

    float qn0 = ndv.x, qn1 = ndv.y, qn2 = ndv.z;

    // ---- pass-through stores (ch1, ch2), NON-TEMPORAL ----
    {
        float* o1p = outb + (size_t)CHF + (size_t)n * 3;
        nts4(o1p, c1v);                    // 4th dword: benign (same value as neighbor's)
        float* o2p = outb + (size_t)2 * CHF + (size_t)n * 3;
        if (!btail) nts4(o2p, edv);        // 4th dword benign within batch
        else { nts1(o2p, edv.x); nts1(o2p + 1, edv.y); nts1(o2p + 2, edv.z); }
    }

    // ---- p-side via f16-packed shuffle (3 bpermutes); boundary lanes load ----
    H2U s0_, s1_, s2_;
    s0_.h = __builtin_amdgcn_cvt_pkrtz(qn0, qn1);     // (n0, n1)
    s1_.h = __builtin_amdgcn_cvt_pkrtz(qn2, edv.x);   // (n2, e0)
    s2_.h = __builtin_amdgcn_cvt_pkrtz(edv.y, edv.z); // (e1, e2)
    unsigned int t0 = __shfl_up(s0_.u, 1);
    unsigned int t1 = __shfl_up(s1_.u, 1);
    unsigned int t2 = __shfl_up(s2_.u, 1);
    if (lane == 0 || n == 0) {
        int p = (n == 0) ? (N_NODES - 1) : (n - 1);
        const float* np_ = inb + (size_t)p * 3;
        const float* epp = inb + (size_t)2 * CHF + (size_t)p * 3;
        H2U a, bb, c;
        a.h  = __builtin_amdgcn_cvt_pkrtz(np_[0], np_[1]);
        bb.h = __builtin_amdgcn_cvt_pkrtz(np_[2], epp[0]);
        c.h  = __builtin_amdgcn_cvt_pkrtz(epp[1], epp[2]);
        t0 = a.u; t1 = bb.u; t2 = c.u;
    }
    H2U u0, u1, u2; u0.u = t0; u1.u = t1; u2.u = t2;
    float pp0 = (float)u0.h[0], pp1 = (float)u0.h[1], pp2 = (float)u1.h[0];
    h2v eh0 = {u1.h[1], u1.h[1]};
    h2v eh1 = {u2.h[0], u2.h[0]};
    h2v eh2 = {u2.h[1], u2.h[1]};

    // ---- layer 1: packed f16 (v_pk_fma_f16), relu -> LDS rows [pos][32 f16] ----
    h2v zz = {(__fp16)0.0f, (__fp16)0.0f};
    unsigned int hp[16];
#pragma unroll
    for (int m = 0; m < 16; ++m) {
        H2U acc, w0, w1_, w2_;
        acc.u = aux[48 + m];
        w0.u  = aux[m];
        w1_.u = aux[16 + m];
        w2_.u = aux[32 + m];
        acc.h = eh0 * w0.h + acc.h;
        acc.h = eh1 * w1_.h + acc.h;
        acc.h = eh2 * w2_.h + acc.h;
        acc.h = __builtin_elementwise_max(acc.h, zz);
        hp[m] = acc.u;
    }
    {
        uint4* row = (uint4*)(L + lane * LSTRIDE);
        row[0] = make_uint4(hp[0],  hp[1],  hp[2],  hp[3]);
        row[1] = make_uint4(hp[4],  hp[5],  hp[6],  hp[7]);
        row[2] = make_uint4(hp[8],  hp[9],  hp[10], hp[11]);
        row[3] = make_uint4(hp[12], hp[13], hp[14], hp[15]);
    }

    // ---- per pos-tile: swapped MFMA2 -> reg-pack -> swapped MFMA3 -> z-write ----
    int r16 = lane & 15;   // C-col = position within tile / B-col
    int q4  = lane >> 4;   // k-group / C-row-group
    U4H8 wb20; wb20.u = wf[lane];
    U4H8 wb21; wb21.u = wf[64 + lane];
    U4H8 wb3;  wb3.u  = wf[128 + lane];
    f32x4 bi0 = *(const f32x4*)(b2 + 4*q4);        // b2[j], j = 4q4 + r  (C-rows)
    f32x4 bi1 = *(const f32x4*)(b2 + 16 + 4*q4);

#pragma unroll
    for (int pt = 0; pt < 4; ++pt) {
        U4H8 hB; hB.u = *(const uint4*)(L + (pt*16 + r16) * LSTRIDE + q4 * 16);
        f32x4 acc0 = bi0;
        f32x4 acc1 = bi1;
        acc0 = __builtin_amdgcn_mfma_f32_16x16x32_f16(wb20.h, hB.h, acc0, 0, 0, 0);
        acc1 = __builtin_amdgcn_mfma_f32_16x16x32_f16(wb21.h, hB.h, acc1, 0, 0, 0);

        // relu+pack in register: lane holds h2[pos][{4q4..4q4+3, 16+4q4..+3}] = B3' frag
        H2U g0, g1, g2, g3;
        g0.h = __builtin_elementwise_max(__builtin_amdgcn_cvt_pkrtz(acc0[0], acc0[1]), zz);
        g1.h = __builtin_elementwise_max(__builtin_amdgcn_cvt_pkrtz(acc0[2], acc0[3]), zz);
        g2.h = __builtin_elementwise_max(__builtin_amdgcn_cvt_pkrtz(acc1[0], acc1[1]), zz);
        g3.h = __builtin_elementwise_max(__builtin_amdgcn_cvt_pkrtz(acc1[2], acc1[3]), zz);
        U4H8 b3f; b3f.u = make_uint4(g0.u, g1.u, g2.u, g3.u);

        f32x4 c3 = __builtin_amdgcn_mfma_f32_16x16x32_f16(wb3.h, b3f.h,
                                                          (f32x4){0.f,0.f,0.f,0.f}, 0, 0, 0);

        // rows c = 4*q4 + r -> q4==0 lanes hold c=0..2 for position pos = pt*16 + r16.
        // ZB overlay: z of position pos lives in row pos>>1's pad, byte 64 + (pos&1)*8.
        if (q4 == 0) {
            int pos = pt*16 + r16;
            H2U za; za.h = __builtin_amdgcn_cvt_pkrtz(c3[0], c3[1]);
            H2U zb; zb.h = __builtin_amdgcn_cvt_pkrtz(c3[2], 0.f);
            *(uint2*)(L + (pos >> 1) * LSTRIDE + 64 + (pos & 1) * 8) = make_uint2(za.u, zb.u);
        }
    }

    // ---- tail: z = r . node[p]; out0 = Wp . [z, node[n]] (NON-TEMPORAL stores) ----
    uint2 zr = *(const uint2*)(L + (lane >> 1) * LSTRIDE + 64 + (lane & 1) * 8);
    H2U za, zb; za.u = zr.x; zb.u = zr.y;
    float z = fmaf((float)za.h[0], pp0,
              fmaf((float)za.h[1], pp1, (float)zb.h[0] * pp2));

    float vo[3];
#pragma unroll
    for (int o = 0; o < 3; ++o) {
        float v = Wp[o*4 + 0] * z;
        v = fmaf(Wp[o*4 + 1], qn0, v);
        v = fmaf(Wp[o*4 + 2], qn1, v);
        v = fmaf(Wp[o*4 + 3], qn2, v);
        vo[o] = v;
    }
    float* o0 = outb + (size_t)n * 3;
    nts2(o0, (f32x2){vo[0], vo[1]});
    nts1(o0 + 2, vo[2]);
}

extern "C" void kernel_launch(void* const* d_in, const int* in_sizes, int n_in,
                              void* d_out, int out_size, void* d_ws, size_t ws_size,
                              hipStream_t stream) {
    const float* in = (const float*)d_in[0];
    const float* W1 = (const float*)d_in[1];
    const float* b1 = (const float*)d_in[2];
    const float* W2 = (const float*)d_in[3];
    const float* b2 = (const float*)d_in[4];
    const float* W3 = (const float*)d_in[5];
    // d_in[6] = Wq — provably unused (softmax weights are exactly 1)
    const float* Wp = (const float*)d_in[7];
    float* out = (float*)d_out;

    uint4* wf = (uint4*)d_ws;                        // 192 * 16 B
    unsigned int* aux = (unsigned int*)(wf + 192);   // 64 * 4 B
    hipLaunchKernelGGL(prep_weights, dim3(1), dim3(256), 0, stream, W1, b1, W2, W3, wf, aux);

    int blocks = TOTAL / 256;   // 25000, exact
    hipLaunchKernelGGL(xattn_kernel, dim3(blocks), dim3(256), 0, stream,
                       in, aux, b2, wf, Wp, out);
}